// Round 7
// baseline (125.466 us; speedup 1.0000x reference)
//
#include <hip/hip_runtime.h>
#include <math.h>

// ConvCaps EM routing, fp32 I/O. n=392 positions, one 512-thread block each.
// R27: ping-pong ILP. R26 post-mortem: rotation bought only 3% — the real
// stall is the in-order serial softmax chain (quad->exp2->reduce->rcp->rr;
// moments blocked on rr), and R26's single v-buffer anti-dependence locked
// compute_v out of that stall window (compiler kept VGPR=100, no rename).
// Fix: two v buffers (va/vb) + manual unroll-2. Per body: exponent chain on
// vPrev, compute_v into vNext (32 independent packed FMAs + load waits fill
// the ~200cy chain stall), moments on vPrev. NOT R16/R19's k-interleave
// (two full chains); one chain + one independent FMA slab.
// VGPR budget: +16 for 2nd buffer; B2 moved to LDS (sB stride-17 conflict-
// free, scalar-pair reads, opaque-offset anti-LICM — R23-proven pattern) to
// stay under the 128 cliff (2 blocks/CU). A2 stays in regs.
// HARD CONSTRAINT: VGPR <= 128. No __launch_bounds__ min-waves ever (R21).
// Dead ends (measured): 768-thread blocks (R21/R22/R23); launch_bounds
// min-waves (R3/R8/R21); LDS prefetch w/o consumer move (R12); 2 pos/block
// (R7); k-interleave both-chains (R16/R19); A&B both LDS @768th (R23);
// permlane16_swap aliased operands (R25: absmax 2.3).

#define NTH 512
#define KK 288
#define KSG 16       // k-groups (512/32)
#define KT 18        // 288 / 16
#define CC 32
#define PS 16
#define EPSF 1e-8f
#define LAMF 1e-3f
#define HL2PI 0.91893853320467274178f   // 0.5*ln(2*pi)
#define LOG2E 1.4426950408889634f

typedef float v2f __attribute__((ext_vector_type(2)));

__device__ __forceinline__ float4 ld4(const float* p){ return *(const float4*)p; }
__device__ __forceinline__ float rcpf(float x){ return __builtin_amdgcn_rcpf(x); }
__device__ __forceinline__ v2f bc2(float s){ return (v2f){s, s}; }
__device__ __forceinline__ v2f fma2(v2f a, v2f b, v2f c){ return __builtin_elementwise_fma(a, b, c); }

// DPP cross-lane reduce steps (VALU pipe ~2-4cyc vs ds_swizzle ~30cyc).
template<int CTRL>
__device__ __forceinline__ float dpp_add(float x){
  const int p = __builtin_amdgcn_update_dpp(0, __builtin_bit_cast(int, x),
                                            CTRL, 0xF, 0xF, true);
  return x + __builtin_bit_cast(float, p);
}
template<int CTRL>
__device__ __forceinline__ float dpp_max(float x){
  const int p = __builtin_amdgcn_update_dpp(0, __builtin_bit_cast(int, x),
                                            CTRL, 0xF, 0xF, true);
  return fmaxf(x, __builtin_bit_cast(float, p));
}
__device__ __forceinline__ float sum32(float s){
  s = dpp_add<0xB1>(s); s = dpp_add<0x4E>(s);
  s = dpp_add<0x141>(s); s = dpp_add<0x140>(s);
  s += __shfl_xor(s, 16);
  return s;
}

extern "C" __global__ void __launch_bounds__(NTH)
convcaps_em_kernel(const float* __restrict__ x, const float* __restrict__ wgt,
                   const float* __restrict__ beta_a, const float* __restrict__ beta_u,
                   float* __restrict__ out)
{
  __shared__ float sP[KK*PS];        // poses, xor-swizzled groups (18432 B)
  __shared__ float sA[KK];           // f = a/(a+eps) (1152 B)
  __shared__ float sPart[8*CC*33];   // wave partials t0|t1[16]|t2[16] (33792 B)
  __shared__ float sMu[CC*17];       // (2176 B)
  __shared__ float sNI2[CC*17];      // -0.5/sigma^2 (2176 B)
  __shared__ float sB[CC*17];        // B = -2*log2e*ni2*mu, stride 17 (2176 B)
  __shared__ float sLs[CC], sLnA[CC], sAo[CC];   // 384 B
  // total ~60.3 KB -> 2 blocks/CU (120.6/160)

  const int tid = threadIdx.x;
  const int n   = blockIdx.x;
  const int b   = n / 49;
  const int r49 = n - b*49;
  const int ohi = r49 / 7;
  const int owi = r49 - ohi*7;

  const float* xw = x + ((size_t)b*16 + (size_t)(ohi*2))*16*544 + (size_t)(owi*2)*544;

  const int c  = tid & 31;    // sweep layout: c in-wave (softmax over c)
  const int ks = tid >> 5;    // k-group 0..15
  const int w  = tid >> 6;    // wave 0..7
  const int cc = tid >> 4;    // stats layout: one thread per (cc, pp)
  const int pp = tid & 15;

  // ---- stage poses (xor-swizzled groups) ----
  for (int idx = tid; idx < KK*PS/4; idx += NTH) {   // 1152 float4s
    const int sp  = idx >> 7;
    const int ch4 = idx & 127;
    const int kh = sp/3, kw = sp - kh*3;
    const float4 v = ld4(&xw[kh*(16*544) + kw*544 + ch4*4]);
    const int k = sp*32 + (ch4 >> 2);
    const int g = ch4 & 3;
    *(float4*)&sP[(k<<4) + ((g ^ ((k>>1)&3))<<2)] = v;
  }
  // ---- stage activations ----
  if (tid < KK/4) {
    const int sp  = tid >> 3;
    const int bc4 = tid & 7;
    const int kh = sp/3, kw = sp - kh*3;
    const float4 v = ld4(&xw[kh*(16*544) + kw*544 + 512 + bc4*4]);
    *(float4*)&sA[sp*32 + bc4*4] = v;
  }
  __syncthreads();
  if (tid < KK) { const float a = sA[tid]; sA[tid] = a * rcpf(a + EPSF); }
  __syncthreads();

  float t0;
  v2f t1[8], t2[8];    // packed moment accumulators

  // ---- stats: reduce + write mu/ni2 AND B (reg diet for sweeps) ----
  auto stats = [&](){
    t0 += __shfl_xor(t0, 32);
#pragma unroll
    for (int q = 0; q < 8; ++q) {
      t1[q].x += __shfl_xor(t1[q].x, 32);
      t1[q].y += __shfl_xor(t1[q].y, 32);
      t2[q].x += __shfl_xor(t2[q].x, 32);
      t2[q].y += __shfl_xor(t2[q].y, 32);
    }
    if ((tid & 32) == 0) {
      float* pr = &sPart[(w*CC + c)*33];
      pr[0] = t0;
#pragma unroll
      for (int q = 0; q < 8; ++q) {
        pr[1 + 2*q]     = t1[q].x;  pr[1 + 2*q + 1]  = t1[q].y;
        pr[17 + 2*q]    = t2[q].x;  pr[17 + 2*q + 1] = t2[q].y;
      }
    }
    __syncthreads();
    {
      float T0 = 0.f, T1 = 0.f, T2 = 0.f;
#pragma unroll
      for (int j = 0; j < 8; ++j) {
        const float* pr = &sPart[(j*CC + cc)*33];
        T0 += pr[0]; T1 += pr[1+pp]; T2 += pr[17+pp];
      }
      const float z   = rcpf(T0 + EPSF);
      const float mu  = T1 * z;
      const float s0  = T0 * z;
      const float var = fmaxf(T2*z - mu*mu*(2.f - s0), 0.f) + EPSF;
      const float ni2 = -0.5f * rcpf(var);
      sMu[cc*17 + pp]  = mu;
      sNI2[cc*17 + pp] = ni2;
      sB[cc*17 + pp]   = (-2.f*LOG2E) * (ni2 * mu);
      float lsum = 0.5f * __logf(var);
      lsum = dpp_add<0xB1>(lsum); lsum = dpp_add<0x4E>(lsum);
      lsum = dpp_add<0x141>(lsum); lsum = dpp_add<0x140>(lsum);
      if (pp == 0) {
        const float cost = (16.f*beta_u[cc] + lsum) * T0;   // r_sum = T0
        const float ao = rcpf(1.f + __expf(-(LAMF*(beta_a[cc] - cost))));
        sAo[cc] = ao; sLnA[cc] = __logf(ao); sLs[cc] = lsum;
      }
    }
    __syncthreads();
  };

  const float4* wg4 = (const float4*)wgt;

  // v = P@W for one k into 8 packed v2f (16 fp32)
  auto compute_v = [&](v2f (&v)[8], const float4 (&P)[4],
                       const float4& W0, const float4& W1,
                       const float4& W2, const float4& W3){
    const v2f w0lo = {W0.x,W0.y}, w0hi = {W0.z,W0.w};
    const v2f w1lo = {W1.x,W1.y}, w1hi = {W1.z,W1.w};
    const v2f w2lo = {W2.x,W2.y}, w2hi = {W2.z,W2.w};
    const v2f w3lo = {W3.x,W3.y}, w3hi = {W3.z,W3.w};
#pragma unroll
    for (int i = 0; i < 4; ++i) {
      v2f lo = bc2(P[i].x) * w0lo;
      lo = fma2(bc2(P[i].y), w1lo, lo);
      lo = fma2(bc2(P[i].z), w2lo, lo);
      lo = fma2(bc2(P[i].w), w3lo, lo);
      v2f hi = bc2(P[i].x) * w0hi;
      hi = fma2(bc2(P[i].y), w1hi, hi);
      hi = fma2(bc2(P[i].z), w2hi, hi);
      hi = fma2(bc2(P[i].w), w3hi, hi);
      v[i*2] = lo; v[i*2+1] = hi;
    }
  };

  // ---- sweep 0 (it=0): r uniform -> rr = f/32, W software-pipelined ----
  t0 = 0.f;
#pragma unroll
  for (int q = 0; q < 8; ++q) { t1[q] = bc2(0.f); t2[q] = bc2(0.f); }
  {
    float4 cw0, cw1, cw2, cw3;
    {
      const size_t base = ((size_t)(ks*32 + c))*4;   // kt=0 -> k=ks
      cw0 = wg4[base]; cw1 = wg4[base+1]; cw2 = wg4[base+2]; cw3 = wg4[base+3];
    }
#pragma unroll 1
    for (int kt = 0; kt < KT; ++kt) {
      const int k = kt*KSG + ks;
      const int kn = ((kt+1 < KT) ? kt+1 : kt)*KSG + ks;
      float4 nw0, nw1, nw2, nw3;
      {
        const size_t base = ((size_t)(kn*32 + c))*4;
        nw0 = wg4[base]; nw1 = wg4[base+1]; nw2 = wg4[base+2]; nw3 = wg4[base+3];
      }
      const v2f w0lo = {cw0.x,cw0.y}, w0hi = {cw0.z,cw0.w};
      const v2f w1lo = {cw1.x,cw1.y}, w1hi = {cw1.z,cw1.w};
      const v2f w2lo = {cw2.x,cw2.y}, w2hi = {cw2.z,cw2.w};
      const v2f w3lo = {cw3.x,cw3.y}, w3hi = {cw3.z,cw3.w};
      const int sw = (k>>1)&3;
      const float* pb = &sP[k<<4];
      const float4 Pi[4] = { ld4(pb + ((0^sw)<<2)), ld4(pb + ((1^sw)<<2)),
                             ld4(pb + ((2^sw)<<2)), ld4(pb + ((3^sw)<<2)) };
      const float rr = sA[k] * (1.0f/32.0f);
      t0 += rr;
      const v2f rr2 = bc2(rr);
#pragma unroll
      for (int i = 0; i < 4; ++i) {
        v2f lo = bc2(Pi[i].x) * w0lo;
        lo = fma2(bc2(Pi[i].y), w1lo, lo);
        lo = fma2(bc2(Pi[i].z), w2lo, lo);
        lo = fma2(bc2(Pi[i].w), w3lo, lo);
        v2f hi = bc2(Pi[i].x) * w0hi;
        hi = fma2(bc2(Pi[i].y), w1hi, hi);
        hi = fma2(bc2(Pi[i].z), w2hi, hi);
        hi = fma2(bc2(Pi[i].w), w3hi, hi);
        const v2f mlo = rr2 * lo, mhi = rr2 * hi;
        t1[i*2]   += mlo;  t2[i*2]   = fma2(mlo, lo, t2[i*2]);
        t1[i*2+1] += mhi;  t2[i*2+1] = fma2(mhi, hi, t2[i*2+1]);
      }
      cw0 = nw0; cw1 = nw1; cw2 = nw2; cw3 = nw3;
    }
  }
  stats();

  // ---- sweeps 1,2: ping-pong. Per body: exponent chain on vP, compute_v
  //      into vN (independent FMAs fill chain stall), moments on vP. ----
  for (int it = 1; it < 3; ++it) {
    // loop-invariant per (sweep, c): A = log2e*ni2 (regs); B in sB (LDS);
    // G = log2e*(Sum ni2*mu^2 + lcv - M)
    v2f A2[8];
    float gsum = 0.f;
#pragma unroll
    for (int q = 0; q < 8; ++q) {
      const v2f m2 = (v2f){ sMu[c*17 + 2*q],  sMu[c*17 + 2*q + 1] };
      const v2f n2 = (v2f){ sNI2[c*17 + 2*q], sNI2[c*17 + 2*q + 1] };
      A2[q] = bc2(LOG2E) * n2;
      const v2f g2 = n2 * m2 * m2;
      gsum += g2.x + g2.y;
    }
    float lcv = sLnA[c] - sLs[c] - 16.f*HL2PI;
    float M = lcv;
    M = dpp_max<0xB1>(M);  M = dpp_max<0x4E>(M);
    M = dpp_max<0x141>(M); M = dpp_max<0x140>(M);
    M = fmaxf(M, __shfl_xor(M, 16));
    const float G = LOG2E*(gsum + lcv - M);

    t0 = 0.f;
#pragma unroll
    for (int q = 0; q < 8; ++q) { t1[q] = bc2(0.f); t2[q] = bc2(0.f); }

    // full softmax+moments (epilogue use)
    auto sm_moments = [&](const v2f (&v)[8], float fA){
      int bo = c*17;
      asm volatile("" : "+v"(bo));
      v2f acc2 = bc2(0.f);
#pragma unroll
      for (int q = 0; q < 8; ++q) {
        const v2f B2 = { sB[bo + 2*q], sB[bo + 2*q + 1] };
        acc2 = fma2(fma2(A2[q], v[q], B2), v[q], acc2);
      }
      const float ex = acc2.x + acc2.y + G;
      const float e = exp2f(ex);
      const float s = sum32(e);
      const float rr = e * rcpf(s + 1e-37f) * fA;
      t0 += rr;
      const v2f rr2 = bc2(rr);
#pragma unroll
      for (int q = 0; q < 8; ++q) {
        const v2f tmp = rr2 * v[q];
        t1[q] += tmp;
        t2[q] = fma2(tmp, v[q], t2[q]);
      }
    };

    // body: process vP (softmax+moments for k-KSG) while computing vN for k
    auto body = [&](v2f (&vP)[8], v2f (&vN)[8], const int k){
      // loads for k (issued first; consumed by compute_v mid-chain)
      const size_t base = ((size_t)(k*32 + c))*4;
      const float4 w0 = wg4[base], w1 = wg4[base+1], w2 = wg4[base+2], w3 = wg4[base+3];
      const float fA = sA[k - KSG];
      const int sw = (k>>1)&3;
      const float* pb = &sP[k<<4];
      const float4 Pi[4] = { ld4(pb + ((0^sw)<<2)), ld4(pb + ((1^sw)<<2)),
                             ld4(pb + ((2^sw)<<2)), ld4(pb + ((3^sw)<<2)) };
      // exponent chain on vP (B streamed from LDS, anti-LICM offset)
      int bo = c*17;
      asm volatile("" : "+v"(bo));
      v2f acc2 = bc2(0.f);
#pragma unroll
      for (int q = 0; q < 8; ++q) {
        const v2f B2 = { sB[bo + 2*q], sB[bo + 2*q + 1] };
        acc2 = fma2(fma2(A2[q], vP[q], B2), vP[q], acc2);
      }
      const float ex = acc2.x + acc2.y + G;
      const float e = exp2f(ex);
      const float s = sum32(e);
      const float rr = e * rcpf(s + 1e-37f) * fA;
      // independent slab: compute vN (fills the chain's stall cycles)
      compute_v(vN, Pi, w0, w1, w2, w3);
      // moments on vP (blocked on rr — by now chain is done)
      t0 += rr;
      const v2f rr2 = bc2(rr);
#pragma unroll
      for (int q = 0; q < 8; ++q) {
        const v2f tmp = rr2 * vP[q];
        t1[q] += tmp;
        t2[q] = fma2(tmp, vP[q], t2[q]);
      }
    };

    v2f va[8], vb[8];
    // prologue (kt=0): load + compute va = v(k0). Latency exposed once.
    {
      const int k = ks;
      const size_t base = ((size_t)(k*32 + c))*4;
      const float4 w0 = wg4[base], w1 = wg4[base+1], w2 = wg4[base+2], w3 = wg4[base+3];
      const int sw = (k>>1)&3;
      const float* pb = &sP[k<<4];
      const float4 Pi[4] = { ld4(pb + ((0^sw)<<2)), ld4(pb + ((1^sw)<<2)),
                             ld4(pb + ((2^sw)<<2)), ld4(pb + ((3^sw)<<2)) };
      compute_v(va, Pi, w0, w1, w2, w3);
    }
#pragma unroll 1
    for (int kt = 1; kt + 1 < KT; kt += 2) {
      body(va, vb, kt*KSG + ks);         // process v(kt-1), compute v(kt)
      body(vb, va, (kt+1)*KSG + ks);     // process v(kt),   compute v(kt+1)
    }
    body(va, vb, (KT-1)*KSG + ks);       // process v(KT-2), compute v(KT-1)
    sm_moments(vb, sA[(KT-1)*KSG + ks]); // process v(KT-1)
    stats();
  }

  // ---- epilogue ----
  out[(size_t)n*544 + tid] = sMu[(tid>>4)*17 + (tid&15)];
  if (tid < CC) out[(size_t)n*544 + 512 + tid] = sAo[tid];
}

extern "C" void kernel_launch(void* const* d_in, const int* in_sizes, int n_in,
                              void* d_out, int out_size, void* d_ws, size_t ws_size,
                              hipStream_t stream) {
  (void)in_sizes; (void)n_in; (void)d_ws; (void)ws_size; (void)out_size;
  const float* x  = (const float*)d_in[0];
  const float* w  = (const float*)d_in[1];
  const float* ba = (const float*)d_in[2];
  const float* bu = (const float*)d_in[3];
  float* out = (float*)d_out;
  convcaps_em_kernel<<<dim3(392), dim3(NTH), 0, stream>>>(x, w, ba, bu, out);
}

// Round 8
// 120.286 us; speedup vs baseline: 1.0431x; 1.0431x over previous
//
#include <hip/hip_runtime.h>
#include <math.h>

// ConvCaps EM routing, fp32 I/O. n=392 positions, one 512-thread block each.
// R28: deferred-moments software pipeline (un-confounded retry of R27's idea).
// R27 post-mortem: ping-pong regressed 5% because (a) asm volatile anti-LICM
// barriers inside the body are scheduling fences (hasSideEffects) blocking
// the very interleave sought, and (b) B2-in-LDS added 8 dependent ds reads at
// the chain head. This round: A2/B2 back in regs (R26-style), NO asm in loop.
// Pipeline: per body, issue loads(k+1) -> quad+exp2 on v(k) (quad split into
// 2 chains to halve serial depth) -> issue 5-step reduce -> MOMENTS OF v(k-1)
// with rr(k-1) (64 independent VALU ops fill the ~70-100cy reduce+rcp
// latency hole, which R26/R27 left empty -> all lockstep waves stalled
// together) -> finalize rr(k) -> compute_v(k+1) into the drained buffer.
// HARD CONSTRAINT: VGPR <= 128 (2 blocks/CU on crit CUs). No
// __launch_bounds__ min-waves ever (R21: 40 VGPR clamp + 1GB spills).
// Dead ends (measured): 768-thread blocks (R21/R22/R23); launch_bounds
// min-waves (R3/R8/R21); LDS prefetch w/o consumer move (R12); 2 pos/block
// (R7); k-interleave both-chains (R16/R19); B2-in-LDS + asm fences in body
// (R27: 77us); permlane16_swap aliased operands (R25: absmax 2.3).
// Best so far: R26 rotation 73.5us (VGPR 100, VALU 40%).

#define NTH 512
#define KK 288
#define KSG 16       // k-groups (512/32)
#define KT 18        // 288 / 16
#define CC 32
#define PS 16
#define EPSF 1e-8f
#define LAMF 1e-3f
#define HL2PI 0.91893853320467274178f   // 0.5*ln(2*pi)
#define LOG2E 1.4426950408889634f

typedef float v2f __attribute__((ext_vector_type(2)));

__device__ __forceinline__ float4 ld4(const float* p){ return *(const float4*)p; }
__device__ __forceinline__ float rcpf(float x){ return __builtin_amdgcn_rcpf(x); }
__device__ __forceinline__ v2f bc2(float s){ return (v2f){s, s}; }
__device__ __forceinline__ v2f fma2(v2f a, v2f b, v2f c){ return __builtin_elementwise_fma(a, b, c); }

// DPP cross-lane reduce steps (VALU pipe ~2-4cyc vs ds_swizzle ~30cyc).
template<int CTRL>
__device__ __forceinline__ float dpp_add(float x){
  const int p = __builtin_amdgcn_update_dpp(0, __builtin_bit_cast(int, x),
                                            CTRL, 0xF, 0xF, true);
  return x + __builtin_bit_cast(float, p);
}
template<int CTRL>
__device__ __forceinline__ float dpp_max(float x){
  const int p = __builtin_amdgcn_update_dpp(0, __builtin_bit_cast(int, x),
                                            CTRL, 0xF, 0xF, true);
  return fmaxf(x, __builtin_bit_cast(float, p));
}
__device__ __forceinline__ float sum32(float s){
  s = dpp_add<0xB1>(s); s = dpp_add<0x4E>(s);
  s = dpp_add<0x141>(s); s = dpp_add<0x140>(s);
  s += __shfl_xor(s, 16);
  return s;
}

extern "C" __global__ void __launch_bounds__(NTH)
convcaps_em_kernel(const float* __restrict__ x, const float* __restrict__ wgt,
                   const float* __restrict__ beta_a, const float* __restrict__ beta_u,
                   float* __restrict__ out)
{
  __shared__ float sP[KK*PS];        // poses, xor-swizzled groups (18432 B)
  __shared__ float sA[KK];           // f = a/(a+eps) (1152 B)
  __shared__ float sPart[8*CC*33];   // wave partials t0|t1[16]|t2[16] (33792 B)
  __shared__ float sMu[CC*17];       // (2176 B)
  __shared__ float sNI2[CC*17];      // -0.5/sigma^2 (2176 B)
  __shared__ float sLs[CC], sLnA[CC], sAo[CC];   // 384 B
  // total ~58.1 KB -> 2 blocks/CU

  const int tid = threadIdx.x;
  const int n   = blockIdx.x;
  const int b   = n / 49;
  const int r49 = n - b*49;
  const int ohi = r49 / 7;
  const int owi = r49 - ohi*7;

  const float* xw = x + ((size_t)b*16 + (size_t)(ohi*2))*16*544 + (size_t)(owi*2)*544;

  const int c  = tid & 31;    // sweep layout: c in-wave (softmax over c)
  const int ks = tid >> 5;    // k-group 0..15
  const int w  = tid >> 6;    // wave 0..7
  const int cc = tid >> 4;    // stats layout: one thread per (cc, pp)
  const int pp = tid & 15;

  // ---- stage poses (xor-swizzled groups) ----
  for (int idx = tid; idx < KK*PS/4; idx += NTH) {   // 1152 float4s
    const int sp  = idx >> 7;
    const int ch4 = idx & 127;
    const int kh = sp/3, kw = sp - kh*3;
    const float4 v = ld4(&xw[kh*(16*544) + kw*544 + ch4*4]);
    const int k = sp*32 + (ch4 >> 2);
    const int g = ch4 & 3;
    *(float4*)&sP[(k<<4) + ((g ^ ((k>>1)&3))<<2)] = v;
  }
  // ---- stage activations ----
  if (tid < KK/4) {
    const int sp  = tid >> 3;
    const int bc4 = tid & 7;
    const int kh = sp/3, kw = sp - kh*3;
    const float4 v = ld4(&xw[kh*(16*544) + kw*544 + 512 + bc4*4]);
    *(float4*)&sA[sp*32 + bc4*4] = v;
  }
  __syncthreads();
  if (tid < KK) { const float a = sA[tid]; sA[tid] = a * rcpf(a + EPSF); }
  __syncthreads();

  float t0;
  v2f t1[8], t2[8];    // packed moment accumulators

  // ---- stats phase (R6-proven layout; unpack pairs at store) ----
  auto stats = [&](){
    t0 += __shfl_xor(t0, 32);
#pragma unroll
    for (int q = 0; q < 8; ++q) {
      t1[q].x += __shfl_xor(t1[q].x, 32);
      t1[q].y += __shfl_xor(t1[q].y, 32);
      t2[q].x += __shfl_xor(t2[q].x, 32);
      t2[q].y += __shfl_xor(t2[q].y, 32);
    }
    if ((tid & 32) == 0) {
      float* pr = &sPart[(w*CC + c)*33];
      pr[0] = t0;
#pragma unroll
      for (int q = 0; q < 8; ++q) {
        pr[1 + 2*q]     = t1[q].x;  pr[1 + 2*q + 1]  = t1[q].y;
        pr[17 + 2*q]    = t2[q].x;  pr[17 + 2*q + 1] = t2[q].y;
      }
    }
    __syncthreads();
    {
      float T0 = 0.f, T1 = 0.f, T2 = 0.f;
#pragma unroll
      for (int j = 0; j < 8; ++j) {
        const float* pr = &sPart[(j*CC + cc)*33];
        T0 += pr[0]; T1 += pr[1+pp]; T2 += pr[17+pp];
      }
      const float z   = rcpf(T0 + EPSF);
      const float mu  = T1 * z;
      const float s0  = T0 * z;
      const float var = fmaxf(T2*z - mu*mu*(2.f - s0), 0.f) + EPSF;
      sMu[cc*17 + pp]  = mu;
      sNI2[cc*17 + pp] = -0.5f * rcpf(var);
      float lsum = 0.5f * __logf(var);
      lsum = dpp_add<0xB1>(lsum); lsum = dpp_add<0x4E>(lsum);
      lsum = dpp_add<0x141>(lsum); lsum = dpp_add<0x140>(lsum);
      if (pp == 0) {
        const float cost = (16.f*beta_u[cc] + lsum) * T0;   // r_sum = T0
        const float ao = rcpf(1.f + __expf(-(LAMF*(beta_a[cc] - cost))));
        sAo[cc] = ao; sLnA[cc] = __logf(ao); sLs[cc] = lsum;
      }
    }
    __syncthreads();
  };

  const float4* wg4 = (const float4*)wgt;

  // v = P@W for one k into 8 packed v2f (16 fp32)
  auto compute_v = [&](v2f (&v)[8], const float4 (&P)[4],
                       const float4& W0, const float4& W1,
                       const float4& W2, const float4& W3){
    const v2f w0lo = {W0.x,W0.y}, w0hi = {W0.z,W0.w};
    const v2f w1lo = {W1.x,W1.y}, w1hi = {W1.z,W1.w};
    const v2f w2lo = {W2.x,W2.y}, w2hi = {W2.z,W2.w};
    const v2f w3lo = {W3.x,W3.y}, w3hi = {W3.z,W3.w};
#pragma unroll
    for (int i = 0; i < 4; ++i) {
      v2f lo = bc2(P[i].x) * w0lo;
      lo = fma2(bc2(P[i].y), w1lo, lo);
      lo = fma2(bc2(P[i].z), w2lo, lo);
      lo = fma2(bc2(P[i].w), w3lo, lo);
      v2f hi = bc2(P[i].x) * w0hi;
      hi = fma2(bc2(P[i].y), w1hi, hi);
      hi = fma2(bc2(P[i].z), w2hi, hi);
      hi = fma2(bc2(P[i].w), w3hi, hi);
      v[i*2] = lo; v[i*2+1] = hi;
    }
  };

  // ---- sweep 0 (it=0): r uniform -> rr = f/32, W software-pipelined ----
  t0 = 0.f;
#pragma unroll
  for (int q = 0; q < 8; ++q) { t1[q] = bc2(0.f); t2[q] = bc2(0.f); }
  {
    float4 cw0, cw1, cw2, cw3;
    {
      const size_t base = ((size_t)(ks*32 + c))*4;   // kt=0 -> k=ks
      cw0 = wg4[base]; cw1 = wg4[base+1]; cw2 = wg4[base+2]; cw3 = wg4[base+3];
    }
#pragma unroll 1
    for (int kt = 0; kt < KT; ++kt) {
      const int k = kt*KSG + ks;
      const int kn = ((kt+1 < KT) ? kt+1 : kt)*KSG + ks;
      float4 nw0, nw1, nw2, nw3;
      {
        const size_t base = ((size_t)(kn*32 + c))*4;
        nw0 = wg4[base]; nw1 = wg4[base+1]; nw2 = wg4[base+2]; nw3 = wg4[base+3];
      }
      const v2f w0lo = {cw0.x,cw0.y}, w0hi = {cw0.z,cw0.w};
      const v2f w1lo = {cw1.x,cw1.y}, w1hi = {cw1.z,cw1.w};
      const v2f w2lo = {cw2.x,cw2.y}, w2hi = {cw2.z,cw2.w};
      const v2f w3lo = {cw3.x,cw3.y}, w3hi = {cw3.z,cw3.w};
      const int sw = (k>>1)&3;
      const float* pb = &sP[k<<4];
      const float4 Pi[4] = { ld4(pb + ((0^sw)<<2)), ld4(pb + ((1^sw)<<2)),
                             ld4(pb + ((2^sw)<<2)), ld4(pb + ((3^sw)<<2)) };
      const float rr = sA[k] * (1.0f/32.0f);
      t0 += rr;
      const v2f rr2 = bc2(rr);
#pragma unroll
      for (int i = 0; i < 4; ++i) {
        v2f lo = bc2(Pi[i].x) * w0lo;
        lo = fma2(bc2(Pi[i].y), w1lo, lo);
        lo = fma2(bc2(Pi[i].z), w2lo, lo);
        lo = fma2(bc2(Pi[i].w), w3lo, lo);
        v2f hi = bc2(Pi[i].x) * w0hi;
        hi = fma2(bc2(Pi[i].y), w1hi, hi);
        hi = fma2(bc2(Pi[i].z), w2hi, hi);
        hi = fma2(bc2(Pi[i].w), w3hi, hi);
        const v2f mlo = rr2 * lo, mhi = rr2 * hi;
        t1[i*2]   += mlo;  t2[i*2]   = fma2(mlo, lo, t2[i*2]);
        t1[i*2+1] += mhi;  t2[i*2+1] = fma2(mhi, hi, t2[i*2+1]);
      }
      cw0 = nw0; cw1 = nw1; cw2 = nw2; cw3 = nw3;
    }
  }
  stats();

  // ---- sweeps 1,2: deferred-moments pipeline.
  //      body(t): loads(k_t) | quad+exp2(v_{t-1}) | reduce | moments(v_{t-2})
  //               | rr_{t-1} | compute_v(v_t into v_{t-2}'s buffer) ----
  for (int it = 1; it < 3; ++it) {
    // loop-invariant per (sweep, c): A = log2e*ni2, B = -2*log2e*ni2*mu,
    // G = log2e*(Sum ni2*mu^2 + lcv - M)
    v2f A2[8], B2[8];
    float gsum = 0.f;
#pragma unroll
    for (int q = 0; q < 8; ++q) {
      const v2f m2 = (v2f){ sMu[c*17 + 2*q],  sMu[c*17 + 2*q + 1] };
      const v2f n2 = (v2f){ sNI2[c*17 + 2*q], sNI2[c*17 + 2*q + 1] };
      const v2f nm = n2 * m2;
      A2[q] = bc2(LOG2E) * n2;
      B2[q] = bc2(-2.f*LOG2E) * nm;
      const v2f g2 = nm * m2;
      gsum += g2.x + g2.y;
    }
    float lcv = sLnA[c] - sLs[c] - 16.f*HL2PI;
    float M = lcv;
    M = dpp_max<0xB1>(M);  M = dpp_max<0x4E>(M);
    M = dpp_max<0x141>(M); M = dpp_max<0x140>(M);
    M = fmaxf(M, __shfl_xor(M, 16));
    const float G = LOG2E*(gsum + lcv - M);

    t0 = 0.f;
#pragma unroll
    for (int q = 0; q < 8; ++q) { t1[q] = bc2(0.f); t2[q] = bc2(0.f); }

    // exponent chain: quad (2 parallel chains) -> exp2
    auto quad_e = [&](const v2f (&v)[8]) -> float {
      v2f accA = bc2(0.f), accB = bc2(0.f);
#pragma unroll
      for (int q = 0; q < 8; q += 2) {
        accA = fma2(fma2(A2[q],   v[q],   B2[q]),   v[q],   accA);
        accB = fma2(fma2(A2[q+1], v[q+1], B2[q+1]), v[q+1], accB);
      }
      const float ex = (accA.x + accA.y) + (accB.x + accB.y) + G;
      return exp2f(ex);   // log2-domain exponent <= ~0
    };
    auto moments = [&](const v2f (&v)[8], float rr){
      t0 += rr;
      const v2f rr2 = bc2(rr);
#pragma unroll
      for (int q = 0; q < 8; ++q) {
        const v2f tmp = rr2 * v[q];
        t1[q] += tmp;
        t2[q] = fma2(tmp, v[q], t2[q]);
      }
    };

    float rrPrev = 0.f;
    // body: expo vP=v(t-1), moments vO=v(t-2) w/ rrPrev, vO <- v(t)
    auto bodyD = [&](v2f (&vP)[8], v2f (&vO)[8], const int t){
      const int kn = t*KSG + ks;
      const size_t base = ((size_t)(kn*32 + c))*4;
      const float4 w0 = wg4[base], w1 = wg4[base+1], w2 = wg4[base+2], w3 = wg4[base+3];
      const float fA = sA[(t-1)*KSG + ks];
      const int sw = (kn>>1)&3;
      const float* pb = &sP[kn<<4];
      const float4 Pi[4] = { ld4(pb + ((0^sw)<<2)), ld4(pb + ((1^sw)<<2)),
                             ld4(pb + ((2^sw)<<2)), ld4(pb + ((3^sw)<<2)) };
      const float e = quad_e(vP);
      const float s = sum32(e);        // 5-hop cross-lane reduce in flight...
      moments(vO, rrPrev);             // ...filled by 64 independent FMAs
      rrPrev = e * rcpf(s + 1e-37f) * fA;
      compute_v(vO, Pi, w0, w1, w2, w3);   // vO drained above; reuse for v(t)
    };

    v2f va[8], vb[8];
    // prologue: compute va = v(0). Latency exposed once.
    {
      const int k = ks;
      const size_t base = ((size_t)(k*32 + c))*4;
      const float4 w0 = wg4[base], w1 = wg4[base+1], w2 = wg4[base+2], w3 = wg4[base+3];
      const int sw = (k>>1)&3;
      const float* pb = &sP[k<<4];
      const float4 Pi[4] = { ld4(pb + ((0^sw)<<2)), ld4(pb + ((1^sw)<<2)),
                             ld4(pb + ((2^sw)<<2)), ld4(pb + ((3^sw)<<2)) };
      compute_v(va, Pi, w0, w1, w2, w3);
    }
    // body0 (t=1): expo v(0), rr0; compute vb = v(1). (no moments yet)
    {
      const int kn = KSG + ks;
      const size_t base = ((size_t)(kn*32 + c))*4;
      const float4 w0 = wg4[base], w1 = wg4[base+1], w2 = wg4[base+2], w3 = wg4[base+3];
      const float fA = sA[ks];
      const int sw = (kn>>1)&3;
      const float* pb = &sP[kn<<4];
      const float4 Pi[4] = { ld4(pb + ((0^sw)<<2)), ld4(pb + ((1^sw)<<2)),
                             ld4(pb + ((2^sw)<<2)), ld4(pb + ((3^sw)<<2)) };
      const float e = quad_e(va);
      const float s = sum32(e);
      rrPrev = e * rcpf(s + 1e-37f) * fA;
      compute_v(vb, Pi, w0, w1, w2, w3);
    }
    // main: 16 bodies, t = 2..17 (KT=18). Invariant at pair top: vb newest.
#pragma unroll 1
    for (int t = 2; t + 1 < KT; t += 2) {
      bodyD(vb, va, t);       // expo v(t-1), moments v(t-2), va <- v(t)
      bodyD(va, vb, t + 1);   // expo v(t),   moments v(t-1), vb <- v(t+1)
    }
    // epilogue: vb = v(17), va = v(16), rrPrev = rr(16)
    {
      const float fA = sA[(KT-1)*KSG + ks];
      const float e = quad_e(vb);
      const float s = sum32(e);
      moments(va, rrPrev);               // v(16) w/ rr(16)
      const float rrL = e * rcpf(s + 1e-37f) * fA;
      moments(vb, rrL);                  // v(17) w/ rr(17)
    }
    stats();
  }

  // ---- epilogue ----
  out[(size_t)n*544 + tid] = sMu[(tid>>4)*17 + (tid&15)];
  if (tid < CC) out[(size_t)n*544 + 512 + tid] = sAo[tid];
}

extern "C" void kernel_launch(void* const* d_in, const int* in_sizes, int n_in,
                              void* d_out, int out_size, void* d_ws, size_t ws_size,
                              hipStream_t stream) {
  (void)in_sizes; (void)n_in; (void)d_ws; (void)ws_size; (void)out_size;
  const float* x  = (const float*)d_in[0];
  const float* w  = (const float*)d_in[1];
  const float* ba = (const float*)d_in[2];
  const float* bu = (const float*)d_in[3];
  float* out = (float*)d_out;
  convcaps_em_kernel<<<dim3(392), dim3(NTH), 0, stream>>>(x, w, ba, bu, out);
}